// Round 1
// 167.082 us; speedup vs baseline: 1.0100x; 1.0100x over previous
//
#include <hip/hip_runtime.h>
#include <stdint.h>

// Problem constants
#define B_   4
#define P_   20000
#define NB_  9
#define WN_  17
#define CI_  64
#define CO_  128
#define PTS  32            // points per block -> 4 waves, each = 1 batch row x 32 points x CO=128
#define NBLK (P_ / PTS)    // 625 blocks

typedef __fp16 f16x8 __attribute__((ext_vector_type(8)));
typedef __fp16 h2    __attribute__((ext_vector_type(2)));
typedef float  f32x16 __attribute__((ext_vector_type(16)));

union H2U { h2 h; uint32_t u; };
union F8U { f16x8 v; h2 h[4]; uint4 u; };

// wsb granule (16B = 8 f16) index: (((m*2+pass)*4 + oloc)*128 + co)*8 ushorts.
// Consecutive co are contiguous -> a wave's 32-lane fragment load is 512B dense.
__global__ void prep_wm(const float* __restrict__ w, ushort* __restrict__ wsb) {
    int i = blockIdx.x * 256 + threadIdx.x;     // 0 .. 17407 (17*2*4*128)
    int m2p  = i >> 9;                          // m*2+pass
    int r    = i & 511;
    int oloc = r >> 7, co = r & 127;
    int m = m2p >> 1, p = m2p & 1;
    const float* src = w + (size_t)m * (CO_ * CI_) + co * CI_ + (p * 4 + oloc) * 8;
    float4 v0 = *(const float4*)(src);
    float4 v1 = *(const float4*)(src + 4);
    F8U h;
    h.h[0] = __builtin_amdgcn_cvt_pkrtz(v0.x, v0.y);
    h.h[1] = __builtin_amdgcn_cvt_pkrtz(v0.z, v0.w);
    h.h[2] = __builtin_amdgcn_cvt_pkrtz(v1.x, v1.y);
    h.h[3] = __builtin_amdgcn_cvt_pkrtz(v1.z, v1.w);
    *(uint4*)&wsb[(size_t)((m2p * 4 + oloc) * 128 + co) * 8] = h.u;
}

template <bool PRE>
__global__ __launch_bounds__(256, 2)
void lasm_fused(const float* __restrict__ in_pc,    // (B,P,CI)    f32
                const float* __restrict__ raw_w,    // (P,NB,WN)   f32
                const float* __restrict__ weights,  // (WN,CO*CI)  f32
                const float* __restrict__ bias,     // (P,CO)      f32
                const int*   __restrict__ nbr,      // (P,NB)      int32
                const ushort* __restrict__ wsb,     // pre-swizzled f16 panel
                float*       __restrict__ out)      // (B,P,CO)    f32
{
    // stride 33 pads: staging writes (addr step 297 words -> bank step 9) and
    // reads (32 consecutive words per (m,n)) are both conflict-free.
    __shared__ __align__(16) uint32_t s_w2[WN_ * NB_ * 33];   // ~20.2 KB

    const int tid  = threadIdx.x;
    const int lane = tid & 63;
    const int wv   = tid >> 6;        // batch row 0..3 (one wave per batch)
    const int arow = lane & 31;       // point-local index / A-row / co within co-tile
    const int q    = lane >> 5;       // k-half
    const int p0   = blockIdx.x * PTS;

    // neighbor ids straight from global (tiny, L2-resident) -> no barrier dep
    int nid[NB_];
    #pragma unroll
    for (int n = 0; n < NB_; ++n)
        nid[n] = nbr[(size_t)(p0 + arow) * NB_ + n];

    const size_t binpc = (size_t)wv * P_ * CI_;

    h2 x[NB_][8];
    auto gather = [&](int pass) {
        const int ch0 = pass * 32 + q * 8;
        #pragma unroll
        for (int n = 0; n < NB_; ++n) {
            if ((uint32_t)nid[n] < (uint32_t)P_) {
                const float* src = in_pc + binpc + (size_t)nid[n] * CI_ + ch0;
                float4 a0 = *(const float4*)(src);
                float4 a1 = *(const float4*)(src + 4);
                float4 b0 = *(const float4*)(src + 16);
                float4 b1 = *(const float4*)(src + 20);
                x[n][0] = __builtin_amdgcn_cvt_pkrtz(a0.x, a0.y);
                x[n][1] = __builtin_amdgcn_cvt_pkrtz(a0.z, a0.w);
                x[n][2] = __builtin_amdgcn_cvt_pkrtz(a1.x, a1.y);
                x[n][3] = __builtin_amdgcn_cvt_pkrtz(a1.z, a1.w);
                x[n][4] = __builtin_amdgcn_cvt_pkrtz(b0.x, b0.y);
                x[n][5] = __builtin_amdgcn_cvt_pkrtz(b0.z, b0.w);
                x[n][6] = __builtin_amdgcn_cvt_pkrtz(b1.x, b1.y);
                x[n][7] = __builtin_amdgcn_cvt_pkrtz(b1.z, b1.w);
            } else {
                h2 z = {(__fp16)0.f, (__fp16)0.f};
                #pragma unroll
                for (int j = 0; j < 8; ++j) x[n][j] = z;
            }
        }
    };

    // issue pass-0 gathers NOW; their latency hides under s_w2 staging below
    gather(0);

    for (int idx = tid; idx < PTS * NB_ * WN_; idx += 256) {
        int pl2 = idx / (NB_ * WN_);
        int rem = idx % (NB_ * WN_);
        int n   = rem / WN_;
        int m   = rem % WN_;
        float wf = raw_w[(size_t)p0 * NB_ * WN_ + idx];
        H2U c; c.h = __builtin_amdgcn_cvt_pkrtz(wf, wf);
        s_w2[(m * NB_ + n) * 33 + pl2] = c.u;
    }
    __syncthreads();   // the ONLY barrier in the kernel

    f32x16 acc[4];
    #pragma unroll
    for (int c = 0; c < 4; ++c)
        #pragma unroll
        for (int j = 0; j < 16; ++j) acc[c][j] = 0.f;

    // B-fragment load, direct global->VGPR (L2-resident panel, no LDS, no barrier)
    auto load_b = [&](int m, int pass, int kk, int c) -> f16x8 {
        int oloc = kk * 2 + q;
        if (PRE) {
            F8U r;
            r.u = *(const uint4*)&wsb[(size_t)(((m * 2 + pass) * 4 + oloc) * 128
                                               + c * 32 + arow) * 8];
            return r.v;
        } else {
            const float* s = weights + (size_t)m * (CO_ * CI_)
                           + (c * 32 + arow) * CI_ + (pass * 4 + oloc) * 8;
            float4 v0 = *(const float4*)(s);
            float4 v1 = *(const float4*)(s + 4);
            F8U r;
            r.h[0] = __builtin_amdgcn_cvt_pkrtz(v0.x, v0.y);
            r.h[1] = __builtin_amdgcn_cvt_pkrtz(v0.z, v0.w);
            r.h[2] = __builtin_amdgcn_cvt_pkrtz(v1.x, v1.y);
            r.h[3] = __builtin_amdgcn_cvt_pkrtz(v1.z, v1.w);
            return r.v;
        }
    };

    // software-pipelined, barrier-free m-loop; each f feeds 4 MFMAs (full CO=128)
    auto mloop = [&](int pass) {
        f16x8 bA[4];
        #pragma unroll
        for (int c = 0; c < 4; ++c) bA[c] = load_b(0, pass, 0, c);

        for (int m = 0; m < WN_; ++m) {
            // per-lane w for its point
            H2U wc[NB_];
            #pragma unroll
            for (int n = 0; n < NB_; ++n) wc[n].u = s_w2[(m * NB_ + n) * 33 + arow];

            // stage-1 in registers: fuse[row=arow][this pass's 4 octs]
            F8U f[2];
            #pragma unroll
            for (int kk = 0; kk < 2; ++kk) {
                #pragma unroll
                for (int r4 = 0; r4 < 4; ++r4) {
                    h2 c2 = {(__fp16)0.f, (__fp16)0.f};
                    #pragma unroll
                    for (int n = 0; n < NB_; ++n) c2 += wc[n].h * x[n][kk * 4 + r4];
                    f[kk].h[r4] = c2;
                }
            }

            f16x8 bB[4];
            #pragma unroll
            for (int c = 0; c < 4; ++c) bB[c] = load_b(m, pass, 1, c);

            #pragma unroll
            for (int c = 0; c < 4; ++c)
                acc[c] = __builtin_amdgcn_mfma_f32_32x32x16_f16(f[0].v, bA[c], acc[c], 0, 0, 0);

            int mn = (m + 1 < WN_) ? m + 1 : m;       // clamped prefetch (in-bounds)
            f16x8 nA[4];
            #pragma unroll
            for (int c = 0; c < 4; ++c) nA[c] = load_b(mn, pass, 0, c);

            #pragma unroll
            for (int c = 0; c < 4; ++c)
                acc[c] = __builtin_amdgcn_mfma_f32_32x32x16_f16(f[1].v, bB[c], acc[c], 0, 0, 0);

            #pragma unroll
            for (int c = 0; c < 4; ++c) bA[c] = nA[c];
        }
    };

    mloop(0);
    gather(1);     // pass-1 gathers issue while pass-0 MFMAs drain
    mloop(1);

    // ---- epilogue: bias + ELU + nontemporal fp32 store ----
    #pragma unroll
    for (int c = 0; c < 4; ++c) {
        int col = c * 32 + arow;
        #pragma unroll
        for (int v = 0; v < 16; ++v) {
            int lr = (v & 3) + 8 * (v >> 2) + 4 * q;   // local row 0..31 in M-tile
            int p  = p0 + lr;
            float val = acc[c][v] + bias[(size_t)p * CO_ + col];
            val = (val > 0.f) ? val : (__expf(val) - 1.f);
            __builtin_nontemporal_store(val, &out[((size_t)wv * P_ + p) * CO_ + col]);
        }
    }
}

extern "C" void kernel_launch(void* const* d_in, const int* in_sizes, int n_in,
                              void* d_out, int out_size, void* d_ws, size_t ws_size,
                              hipStream_t stream) {
    const float* in_pc   = (const float*)d_in[0];
    const float* raw_w   = (const float*)d_in[1];
    const float* weights = (const float*)d_in[2];
    const float* bias    = (const float*)d_in[3];
    const int*   nbr     = (const int*)  d_in[4];
    float* out = (float*)d_out;

    const size_t need = (size_t)WN_ * 2 * 4096 * sizeof(ushort);   // 278,528 B
    if (d_ws != nullptr && ws_size >= need) {
        ushort* wsb = (ushort*)d_ws;
        prep_wm<<<dim3(WN_ * 2 * 512 / 256), dim3(256), 0, stream>>>(weights, wsb);
        lasm_fused<true><<<dim3(NBLK), dim3(256), 0, stream>>>(
            in_pc, raw_w, weights, bias, nbr, wsb, out);
    } else {
        lasm_fused<false><<<dim3(NBLK), dim3(256), 0, stream>>>(
            in_pc, raw_w, weights, bias, nbr, nullptr, out);
    }
}